// Round 1
// baseline (180.075 us; speedup 1.0000x reference)
//
#include <hip/hip_runtime.h>
#include <math.h>

constexpr int B = 64;
constexpr int L = 4096;
constexpr int C = 256;
constexpr int H = 32;

// ---------------- Pass 1: column sums over L ----------------
// grid = B * NCHUNK blocks, 256 threads. Each block handles ROWS rows of one
// batch; thread t owns float4-column (t&63), row-phase (t>>6). Fully coalesced
// 16B/lane loads. Block-local LDS combine, then one atomicAdd per (b,c).
constexpr int NCHUNK = 32;
constexpr int ROWS = L / NCHUNK;  // 128

__global__ __launch_bounds__(256) void se_reduce(const float* __restrict__ in,
                                                 float* __restrict__ s) {
    const int b = blockIdx.x / NCHUNK;
    const int chunk = blockIdx.x % NCHUNK;
    const int t = threadIdx.x;
    const int c4 = t & 63;  // float4 column group (C/4 = 64)
    const int r0 = t >> 6;  // 0..3

    const float4* base = reinterpret_cast<const float4*>(
        in + (size_t)b * L * C + (size_t)chunk * ROWS * C);

    float4 acc = make_float4(0.f, 0.f, 0.f, 0.f);
    for (int r = r0; r < ROWS; r += 4) {
        float4 v = base[(size_t)r * (C / 4) + c4];
        acc.x += v.x; acc.y += v.y; acc.z += v.z; acc.w += v.w;
    }

    __shared__ float4 red[4][C / 4];
    red[r0][c4] = acc;
    __syncthreads();
    if (r0 == 0) {
        float4 v0 = red[0][c4], v1 = red[1][c4], v2 = red[2][c4], v3 = red[3][c4];
        float sum0 = v0.x + v1.x + v2.x + v3.x;
        float sum1 = v0.y + v1.y + v2.y + v3.y;
        float sum2 = v0.z + v1.z + v2.z + v3.z;
        float sum3 = v0.w + v1.w + v2.w + v3.w;
        float* dst = &s[b * C + c4 * 4];
        atomicAdd(dst + 0, sum0);
        atomicAdd(dst + 1, sum1);
        atomicAdd(dst + 2, sum2);
        atomicAdd(dst + 3, sum3);
    }
}

// ---------------- Pass 2: tiny gate MLP ----------------
// grid = B, block = C (256). s -> mean -> relu(s@w1+b1) -> sigmoid(e@w2+b2).
__global__ __launch_bounds__(256) void se_gate(const float* __restrict__ s,
                                               const float* __restrict__ w1,
                                               const float* __restrict__ b1,
                                               const float* __restrict__ w2,
                                               const float* __restrict__ b2,
                                               float* __restrict__ g) {
    const int b = blockIdx.x;
    const int t = threadIdx.x;

    __shared__ float sm[C];
    __shared__ float em[H];

    sm[t] = s[b * C + t] * (1.0f / (float)L);
    __syncthreads();

    if (t < H) {
        float acc = b1[t];
        #pragma unroll 8
        for (int c = 0; c < C; ++c) acc += sm[c] * w1[c * H + t];
        em[t] = fmaxf(acc, 0.0f);
    }
    __syncthreads();

    float acc = b2[t];
    #pragma unroll
    for (int h = 0; h < H; ++h) acc += em[h] * w2[h * C + t];
    g[b * C + t] = 1.0f / (1.0f + expf(-acc));
}

// ---------------- Pass 3: broadcast scale ----------------
// Grid-stride float4 multiply. Chunks iterated in REVERSE so the tail of the
// input (most recently streamed through L3 by pass 1) is re-read first.
constexpr size_t TOT4 = (size_t)B * L * C / 4;  // 16,777,216
constexpr int SCALE_BLOCKS = 2048;
constexpr int SCALE_THREADS = 256;

__global__ __launch_bounds__(256) void se_scale(const float4* __restrict__ in,
                                                const float* __restrict__ g,
                                                float4* __restrict__ out) {
    const size_t stride = (size_t)SCALE_BLOCKS * SCALE_THREADS;  // 524288
    const size_t nsteps = TOT4 / stride;                         // 32
    const size_t tid = (size_t)blockIdx.x * SCALE_THREADS + threadIdx.x;
    const float4* g4 = reinterpret_cast<const float4*>(g);

    for (size_t k = nsteps; k-- > 0;) {
        const size_t i = k * stride + tid;
        float4 v = in[i];
        const size_t b = i >> 18;            // i / (L*C/4), L*C/4 = 2^18
        const int c4 = (int)(i & (C / 4 - 1));
        const float4 gv = g4[b * (C / 4) + c4];
        v.x *= gv.x; v.y *= gv.y; v.z *= gv.z; v.w *= gv.w;
        out[i] = v;
    }
}

extern "C" void kernel_launch(void* const* d_in, const int* in_sizes, int n_in,
                              void* d_out, int out_size, void* d_ws, size_t ws_size,
                              hipStream_t stream) {
    const float* in = (const float*)d_in[0];
    const float* w1 = (const float*)d_in[1];
    const float* b1 = (const float*)d_in[2];
    const float* w2 = (const float*)d_in[3];
    const float* b2 = (const float*)d_in[4];
    float* out = (float*)d_out;

    float* s = (float*)d_ws;   // B*C floats (64 KB) — column sums
    float* g = s + B * C;      // B*C floats (64 KB) — gates

    hipMemsetAsync(s, 0, B * C * sizeof(float), stream);
    se_reduce<<<B * NCHUNK, 256, 0, stream>>>(in, s);
    se_gate<<<B, C, 0, stream>>>(s, w1, b1, w2, b2, g);
    se_scale<<<SCALE_BLOCKS, SCALE_THREADS, 0, stream>>>(
        reinterpret_cast<const float4*>(in), g, reinterpret_cast<float4*>(out));
}

// Round 3
// 147.918 us; speedup vs baseline: 1.2174x; 1.2174x over previous
//
#include <hip/hip_runtime.h>
#include <math.h>

constexpr int B = 64;
constexpr int L = 4096;
constexpr int C = 256;
constexpr int H = 32;

constexpr int NCHUNK = 32;
constexpr int ROWS = L / NCHUNK;  // 128

typedef float v4f __attribute__((ext_vector_type(4)));

// ---------------- Pass 1: per-chunk column sums (no atomics) ----------------
// grid = B*NCHUNK blocks, 256 threads. Thread t owns float4-column (t&63),
// row-phase (t>>6). Writes one 256-float partial row per block to ws.
__global__ __launch_bounds__(256) void se_reduce(const float* __restrict__ in,
                                                 float* __restrict__ partial) {
    const int b = blockIdx.x / NCHUNK;
    const int chunk = blockIdx.x % NCHUNK;
    const int t = threadIdx.x;
    const int c4 = t & 63;
    const int r0 = t >> 6;

    const v4f* base = reinterpret_cast<const v4f*>(
        in + (size_t)b * L * C + (size_t)chunk * ROWS * C);

    v4f acc = (v4f)(0.f);
    for (int r = r0; r < ROWS; r += 4) {
        acc += base[(size_t)r * (C / 4) + c4];
    }

    __shared__ v4f red[4][C / 4];
    red[r0][c4] = acc;
    __syncthreads();
    if (r0 == 0) {
        v4f s = red[0][c4] + red[1][c4] + red[2][c4] + red[3][c4];
        reinterpret_cast<v4f*>(partial + (size_t)blockIdx.x * C)[c4] = s;
    }
}

// ---------------- Pass 2: fold partials + tiny gate MLP ----------------
// grid = B, block = C (256).
__global__ __launch_bounds__(256) void se_gate(const float* __restrict__ partial,
                                               const float* __restrict__ w1,
                                               const float* __restrict__ b1,
                                               const float* __restrict__ w2,
                                               const float* __restrict__ b2,
                                               float* __restrict__ g) {
    const int b = blockIdx.x;
    const int t = threadIdx.x;

    __shared__ float sm[C];
    __shared__ float em[H];

    float acc = 0.f;
    const float* p = partial + (size_t)b * NCHUNK * C + t;
    #pragma unroll 8
    for (int k = 0; k < NCHUNK; ++k) acc += p[(size_t)k * C];
    sm[t] = acc * (1.0f / (float)L);
    __syncthreads();

    if (t < H) {
        float a1 = b1[t];
        #pragma unroll 8
        for (int c = 0; c < C; ++c) a1 += sm[c] * w1[c * H + t];
        em[t] = fmaxf(a1, 0.0f);
    }
    __syncthreads();

    float a2 = b2[t];
    #pragma unroll
    for (int h = 0; h < H; ++h) a2 += em[h] * w2[h * C + t];
    g[b * C + t] = 1.0f / (1.0f + expf(-a2));
}

// ---------------- Pass 3: broadcast scale, non-temporal stores ----------------
constexpr size_t TOT4 = (size_t)B * L * C / 4;  // 16,777,216
constexpr int SCALE_BLOCKS = 2048;
constexpr int SCALE_THREADS = 256;

__global__ __launch_bounds__(256) void se_scale(const v4f* __restrict__ in,
                                                const float* __restrict__ g,
                                                v4f* __restrict__ out) {
    const size_t stride = (size_t)SCALE_BLOCKS * SCALE_THREADS;  // 524288
    const size_t nsteps = TOT4 / stride;                         // 32
    const size_t tid = (size_t)blockIdx.x * SCALE_THREADS + threadIdx.x;
    const v4f* g4 = reinterpret_cast<const v4f*>(g);

    // Reverse order: re-read the most recently L3-resident data first.
    for (size_t k = nsteps; k-- > 0;) {
        const size_t i = k * stride + tid;
        v4f v = in[i];
        const size_t b = i >> 18;            // L*C/4 = 2^18
        const int c4 = (int)(i & (C / 4 - 1));
        const v4f gv = g4[b * (C / 4) + c4];
        v *= gv;
        // Non-temporal: don't allocate the output stream in cache, so the
        // input stays Infinity-Cache-resident for the re-read.
        __builtin_nontemporal_store(v, &out[i]);
    }
}

extern "C" void kernel_launch(void* const* d_in, const int* in_sizes, int n_in,
                              void* d_out, int out_size, void* d_ws, size_t ws_size,
                              hipStream_t stream) {
    const float* in = (const float*)d_in[0];
    const float* w1 = (const float*)d_in[1];
    const float* b1 = (const float*)d_in[2];
    const float* w2 = (const float*)d_in[3];
    const float* b2 = (const float*)d_in[4];
    float* out = (float*)d_out;

    float* partial = (float*)d_ws;               // B*NCHUNK*C floats = 2 MB
    float* g = partial + (size_t)B * NCHUNK * C; // B*C floats = 64 KB

    se_reduce<<<B * NCHUNK, 256, 0, stream>>>(in, partial);
    se_gate<<<B, 256, 0, stream>>>(partial, w1, b1, w2, b2, g);
    se_scale<<<SCALE_BLOCKS, SCALE_THREADS, 0, stream>>>(
        reinterpret_cast<const v4f*>(in), g, reinterpret_cast<v4f*>(out));
}